// Round 7
// baseline (14093.977 us; speedup 1.0000x reference)
//
#include <hip/hip_runtime.h>
#include <hip/hip_bf16.h>

#define T_STEPS 1024
#define NWG     64

typedef __attribute__((ext_vector_type(8))) short          bf16x8;
typedef __attribute__((ext_vector_type(4))) float          f32x4;
typedef __attribute__((ext_vector_type(8))) unsigned short u16x8;
typedef unsigned long long ull;

static __device__ __forceinline__ unsigned short f2bf_bits(float f) {
    union { __hip_bfloat16 h; unsigned short u; } cv;
    cv.h = __float2bfloat16(f);
    return cv.u;
}

// ---------------------------------------------------------------------------
// P1: fold ln_g into weights, cast bf16, emit in MFMA B-fragment order.
// Chunk layout: [g][part][tn][kstep][lane][e]
//   k  = part*512 + kstep*32 + (lane>>4)*8 + e
//   c  = tn*16 + (lane&15);  n = (c>>3)*512 + g*8 + (c&7)
// ---------------------------------------------------------------------------
__global__ __launch_bounds__(256) void pack_weights(
    const float* __restrict__ Wf, const float* __restrict__ Wi,
    const float* __restrict__ Wg, const float* __restrict__ Wo,
    const float* __restrict__ ln_g, __hip_bfloat16* __restrict__ pack)
{
    __shared__ unsigned short tile[512 * 32];   // [k_local][c]
    const int blk = blockIdx.x;
    const int g = blk >> 1, part = blk & 1;
    const int tid = threadIdx.x;

    for (int idx = tid; idx < 512 * 32; idx += 256) {
        int kl = idx >> 5, c = idx & 31;
        int q = c >> 3, jl = c & 7;
        int k = part * 512 + kl;
        const float* W = (q == 0) ? Wf : ((q == 1) ? Wi : ((q == 2) ? Wg : Wo));
        float v = W[k * 512 + g * 8 + jl] * ln_g[k];
        tile[kl * 32 + c] = f2bf_bits(v);
    }
    __syncthreads();

    unsigned short* out = (unsigned short*)(pack + (size_t)blk * 16384);
    for (int s = tid; s < 2048; s += 256) {        // slot = tn*1024 + ks*64 + l
        int tn = s >> 10, ks = (s >> 6) & 15, l = s & 63;
        u16x8 v;
#pragma unroll
        for (int e = 0; e < 8; ++e) {
            int klocal = ks * 32 + ((l >> 4) * 8) + e;
            int c = tn * 16 + (l & 15);
            v[e] = tile[klocal * 32 + c];
        }
        *(u16x8*)(out + (size_t)s * 8) = v;
    }
}

// ---------------------------------------------------------------------------
// P2: S[n] = sum_k ln_g[k]*W[k,n],  C[n] = sum_k ln_b[k]*W[k,n] + bias[n]
// ---------------------------------------------------------------------------
__global__ __launch_bounds__(256) void compute_sc(
    const float* __restrict__ Wf, const float* __restrict__ Wi,
    const float* __restrict__ Wg, const float* __restrict__ Wo,
    const float* __restrict__ bf_, const float* __restrict__ bi_,
    const float* __restrict__ bg_, const float* __restrict__ bo_,
    const float* __restrict__ ln_g, const float* __restrict__ ln_b,
    float* __restrict__ S, float* __restrict__ C)
{
    int n = blockIdx.x * 256 + threadIdx.x;        // 0..2047
    int q = n >> 9, j = n & 511;
    const float* W = (q == 0) ? Wf : ((q == 1) ? Wi : ((q == 2) ? Wg : Wo));
    const float* bb = (q == 0) ? bf_ : ((q == 1) ? bi_ : ((q == 2) ? bg_ : bo_));
    float accS = 0.f, accC = 0.f;
    for (int k = 0; k < 1024; ++k) {
        float w = W[k * 512 + j];
        accS += ln_g[k] * w;
        accC += ln_b[k] * w;
    }
    S[n] = accS;
    C[n] = accC + bb[j];
}

// ---------------------------------------------------------------------------
// P3: x -> bf16 copy + per-row sum / sumsq (fp32). One wave per (t,b) row.
// ---------------------------------------------------------------------------
__global__ __launch_bounds__(256) void prep_x(
    const float* __restrict__ x, __hip_bfloat16* __restrict__ xb,
    float* __restrict__ sx, float* __restrict__ sq)
{
    const int wave = threadIdx.x >> 6, lane = threadIdx.x & 63;
    const long row = (long)blockIdx.x * 4 + wave;  // 0..65535
    const float* src = x + row * 512 + lane * 8;
    float4 a = *(const float4*)src;
    float4 b = *(const float4*)(src + 4);
    float vals[8] = {a.x, a.y, a.z, a.w, b.x, b.y, b.z, b.w};
    u16x8 o;
    float s = 0.f, qq = 0.f;
#pragma unroll
    for (int e = 0; e < 8; ++e) {
        s += vals[e];
        qq += vals[e] * vals[e];
        o[e] = f2bf_bits(vals[e]);
    }
    *(u16x8*)((unsigned short*)xb + row * 512 + lane * 8) = o;
#pragma unroll
    for (int d = 1; d < 64; d <<= 1) {
        s  += __shfl_xor(s, d);
        qq += __shfl_xor(qq, d);
    }
    if (lane == 0) { sx[row] = s; sq[row] = qq; }
}

// ---------------------------------------------------------------------------
// Main persistent kernel: 64 WGs x 512 threads.
// Waves 0-3 = h-waves (m = wave): FULL-K h-GEMM for rows [16m,16m+16),
//   local LN stats, gates, publish, per-(WG,m) flag — NO __syncthreads on
//   the critical path. Consumer wave m waits only on producer waves m of
//   all WGs (one flag word per lane).
// Waves 4-7 = x-waves (m = wave-4): zX(t+1) in shadow, single-buffer
//   prefetched A-frags; barrier is raw lgkmcnt-only so prefetch stays live.
// stacked[t-1] written by consumers (coalesced nt) from loaded h words.
// ---------------------------------------------------------------------------
__global__ __launch_bounds__(512, 2) void qlstm_main(
    const float* __restrict__ x,
    const __hip_bfloat16* __restrict__ pack,
    const float* __restrict__ Sarr, const float* __restrict__ Carr,
    const __hip_bfloat16* __restrict__ xb,
    const float* __restrict__ sx, const float* __restrict__ sq,
    unsigned short* __restrict__ hxb,   // [2][64][512] bf16 (zeroed)
    unsigned int* __restrict__ flags,   // [64 WG][16 u32] (zeroed)
    float* __restrict__ out)            // stacked | hx | cx (fp32)
{
    const int g = blockIdx.x;
    const int tid = threadIdx.x;
    const int wave = tid >> 6, lane = tid & 63;
    const bool isH = wave < 4;
    const int m = isH ? wave : (wave - 4);

    __shared__ float zXs[2][64][33];    // [parity][row][col32]
    __shared__ float zHs[64][33];
    __shared__ float rsS[64], rsQ[64];
    __shared__ float Scol[32], Ccol[32];

    const int arow = m * 16 + (lane & 15);
    const int acol = (lane >> 4) * 8;
    const int r0l = (lane >> 4) * 4, c0 = lane & 15;
    const int grow = m * 16 + (lane >> 2);   // gate row
    const int gcp  = (lane & 3) * 2;         // gate col pair (WG-local)

    if (isH) {
        if (wave == 0 && lane < 32) {
            int n = (lane >> 3) * 512 + g * 8 + (lane & 7);
            Scol[lane] = Sarr[n];
            Ccol[lane] = Carr[n];
        }
        // Full-K h B-fragments: 2 ntiles x 16 ksteps x 4 VGPR = 128 VGPR.
        bf16x8 Bh0[16], Bh1[16];
        {
            const bf16x8* ph = (const bf16x8*)(pack + (size_t)(g * 2 + 1) * 16384);
#pragma unroll
            for (int ks = 0; ks < 16; ++ks) {
                Bh0[ks] = ph[ks * 64 + lane];
                Bh1[ks] = ph[1024 + ks * 64 + lane];
            }
        }
        float cxA = 0.f, cxB = 0.f;
        __syncthreads();

        for (int t = 0; t < T_STEPS; ++t) {
            const int p = t & 1;

            // recurrence-independent loads (nt), issued before the spin
            const float* xp = x + (size_t)t * 32768 + grow * 512 + g * 8 + gcp;
            float xr0 = __builtin_nontemporal_load(xp);
            float xr1 = __builtin_nontemporal_load(xp + 1);
            float sxv = __builtin_nontemporal_load(sx + t * 64 + grow);
            float sqv = __builtin_nontemporal_load(sq + t * 64 + grow);

            // ---- spin: lane l polls flags[l][m] only ----
            if (t) {
                const unsigned int* fp_ = flags + lane * 16 + m;
                int slp = 0;
                for (;;) {
                    unsigned f = __hip_atomic_load(fp_, __ATOMIC_RELAXED,
                                                   __HIP_MEMORY_SCOPE_AGENT);
                    if (__all((int)f >= t)) break;
                    if      (slp == 0) __builtin_amdgcn_s_sleep(1);
                    else if (slp == 1) __builtin_amdgcn_s_sleep(2);
                    else if (slp == 2) __builtin_amdgcn_s_sleep(4);
                    else               __builtin_amdgcn_s_sleep(8);
                    if (slp < 3) ++slp;
                }
                asm volatile("" ::: "memory");
            }

            // ---- coherent h loads: full row slice, 32 x 8B per lane ----
            ull hw[32];
            {
                const ull* hp = (const ull*)hxb + (size_t)p * 8192;
                const int eb = (arow * 512 + acol) >> 2;
#pragma unroll
                for (int ks = 0; ks < 16; ++ks) {
                    hw[2 * ks]     = __hip_atomic_load(hp + eb + ks * 8,
                                        __ATOMIC_RELAXED, __HIP_MEMORY_SCOPE_AGENT);
                    hw[2 * ks + 1] = __hip_atomic_load(hp + eb + ks * 8 + 1,
                                        __ATOMIC_RELAXED, __HIP_MEMORY_SCOPE_AGENT);
                }
            }

            // ---- h-GEMM (full K, 32 MFMA) ----
            f32x4 h0 = {0.f, 0.f, 0.f, 0.f}, h1 = {0.f, 0.f, 0.f, 0.f};
#pragma unroll
            for (int ks = 0; ks < 16; ++ks) {
                union { ull u[2]; bf16x8 v; } cv;
                cv.u[0] = hw[2 * ks]; cv.u[1] = hw[2 * ks + 1];
                h0 = __builtin_amdgcn_mfma_f32_16x16x32_bf16(cv.v, Bh0[ks], h0, 0, 0, 0);
                h1 = __builtin_amdgcn_mfma_f32_16x16x32_bf16(cv.v, Bh1[ks], h1, 0, 0, 0);
            }

            // ---- local LN stats (full row within 4 lanes) ----
            {
                float s = 0.f, q = 0.f;
#pragma unroll
                for (int i = 0; i < 32; ++i) {
                    unsigned lo = (unsigned)hw[i], hi = (unsigned)(hw[i] >> 32);
                    float f0 = __uint_as_float(lo << 16);
                    float f1 = __uint_as_float(lo & 0xffff0000u);
                    float f2 = __uint_as_float(hi << 16);
                    float f3 = __uint_as_float(hi & 0xffff0000u);
                    s += (f0 + f1) + (f2 + f3);
                    q = fmaf(f0, f0, fmaf(f1, f1, fmaf(f2, f2, fmaf(f3, f3, q))));
                }
                s += __shfl_xor(s, 16); q += __shfl_xor(q, 16);
                s += __shfl_xor(s, 32); q += __shfl_xor(q, 32);
                if (lane < 16) { rsS[m * 16 + lane] = s; rsQ[m * 16 + lane] = q; }
            }

            // ---- zH dump (same-wave rows only; no barrier needed) ----
#pragma unroll
            for (int r = 0; r < 4; ++r) {
                zHs[m * 16 + r0l + r][c0]      = h0[r];
                zHs[m * 16 + r0l + r][16 + c0] = h1[r];
            }

            // ---- gates for (grow, cols g*8+gcp, +1) ----
            float hv0, hv1;
            {
                float hs = rsS[grow], hq = rsQ[grow];
                float mu = (sxv + hs) * (1.f / 1024.f);
                float var = (sqv + hq) * (1.f / 1024.f) - mu * mu;
                float rs = rsqrtf(var + 1e-5f);
#pragma unroll
                for (int d = 0; d < 2; ++d) {
                    int cl = gcp + d;
                    float z0 = zXs[p][grow][cl]      + zHs[grow][cl];
                    float z1 = zXs[p][grow][8 + cl]  + zHs[grow][8 + cl];
                    float z2 = zXs[p][grow][16 + cl] + zHs[grow][16 + cl];
                    float z3 = zXs[p][grow][24 + cl] + zHs[grow][24 + cl];
                    float zf = rs * (z0 - mu * Scol[cl])      + Ccol[cl];
                    float zi = rs * (z1 - mu * Scol[8 + cl])  + Ccol[8 + cl];
                    float zg = rs * (z2 - mu * Scol[16 + cl]) + Ccol[16 + cl];
                    float zo = rs * (z3 - mu * Scol[24 + cl]) + Ccol[24 + cl];
                    float f  = 1.f / (1.f + __expf(-zf));
                    float i_ = 1.f / (1.f + __expf(-zi));
                    float gg = 2.f / (1.f + __expf(-2.f * zg)) - 1.f;
                    float o_ = 1.f / (1.f + __expf(-zo));
                    float cxv = (d == 0) ? cxA : cxB;
                    cxv = f * cxv + i_ * gg;
                    float th = 2.f / (1.f + __expf(-2.f * cxv)) - 1.f;
                    float hvv = o_ * th + ((d == 0) ? xr0 : xr1);
                    if (d == 0) { cxA = cxv; hv0 = hvv; }
                    else        { cxB = cxv; hv1 = hvv; }
                }
            }

            // ---- publish (sc1) + drain + per-wave flag ----
            if (t + 1 < T_STEPS) {
                unsigned vv = (unsigned)f2bf_bits(hv0) |
                              ((unsigned)f2bf_bits(hv1) << 16);
                ull v01 = (ull)vv |
                    ((ull)(unsigned)__shfl_xor((int)vv, 1) << 32);
                if ((lane & 1) == 0) {
                    ull* hd = (ull*)hxb +
                        (((size_t)(p ^ 1) * 32768 + grow * 512 + g * 8 + gcp) >> 2);
                    __hip_atomic_store(hd, v01, __ATOMIC_RELAXED,
                                       __HIP_MEMORY_SCOPE_AGENT);
                }
                asm volatile("s_waitcnt vmcnt(0)" ::: "memory");
                if (lane == 0) {
                    __hip_atomic_store(flags + g * 16 + m, (unsigned)(t + 1),
                                       __ATOMIC_RELAXED, __HIP_MEMORY_SCOPE_AGENT);
                }
            }

            // ---- shadow: stacked[t-1] from loaded h words (coalesced, nt) ----
            if (t) {
                float* ob = out + (size_t)(t - 1) * 32768 + arow * 512 + acol;
#pragma unroll
                for (int ks = 0; ks < 16; ++ks) {
                    ull w0 = hw[2 * ks], w1 = hw[2 * ks + 1];
                    f32x4 o0, o1;
                    unsigned lo = (unsigned)w0, hi = (unsigned)(w0 >> 32);
                    o0[0] = __uint_as_float(lo << 16);
                    o0[1] = __uint_as_float(lo & 0xffff0000u);
                    o0[2] = __uint_as_float(hi << 16);
                    o0[3] = __uint_as_float(hi & 0xffff0000u);
                    lo = (unsigned)w1; hi = (unsigned)(w1 >> 32);
                    o1[0] = __uint_as_float(lo << 16);
                    o1[1] = __uint_as_float(lo & 0xffff0000u);
                    o1[2] = __uint_as_float(hi << 16);
                    o1[3] = __uint_as_float(hi & 0xffff0000u);
                    __builtin_nontemporal_store(o0, (f32x4*)(ob + ks * 32));
                    __builtin_nontemporal_store(o1, (f32x4*)(ob + ks * 32 + 4));
                }
            }
            if (t == T_STEPS - 1) {
                size_t b0 = (size_t)(T_STEPS - 1) * 32768 + grow * 512 + g * 8 + gcp;
                out[b0] = hv0; out[b0 + 1] = hv1;
                size_t b1 = (size_t)T_STEPS * 32768 + grow * 512 + g * 8 + gcp;
                out[b1] = hv0; out[b1 + 1] = hv1;
                out[b1 + 32768] = cxA; out[b1 + 32769] = cxB;
            }

            asm volatile("s_waitcnt lgkmcnt(0)\ns_barrier" ::: "memory");
            __builtin_amdgcn_sched_barrier(0);
        }
    } else {
        // ---------------- x-waves ----------------
        bf16x8 Bx0[16], Bx1[16];
        {
            const bf16x8* px = (const bf16x8*)(pack + (size_t)(g * 2 + 0) * 16384);
#pragma unroll
            for (int ks = 0; ks < 16; ++ks) {
                Bx0[ks] = px[ks * 64 + lane];
                Bx1[ks] = px[1024 + ks * 64 + lane];
            }
        }
        bf16x8 afr[16];
        auto LOADF = [&](int tt) {
            const bf16x8* Ap = (const bf16x8*)(xb + (size_t)tt * 32768
                                               + arow * 512 + acol);
#pragma unroll
            for (int ks = 0; ks < 16; ++ks)
                afr[ks] = __builtin_nontemporal_load(Ap + ks * 4);
        };
        auto XG = [&](int par) {
            f32x4 a0 = {0.f, 0.f, 0.f, 0.f}, a1 = {0.f, 0.f, 0.f, 0.f};
#pragma unroll
            for (int ks = 0; ks < 16; ++ks) {
                a0 = __builtin_amdgcn_mfma_f32_16x16x32_bf16(afr[ks], Bx0[ks], a0, 0, 0, 0);
                a1 = __builtin_amdgcn_mfma_f32_16x16x32_bf16(afr[ks], Bx1[ks], a1, 0, 0, 0);
            }
#pragma unroll
            for (int r = 0; r < 4; ++r) {
                zXs[par][m * 16 + r0l + r][c0]      = a0[r];
                zXs[par][m * 16 + r0l + r][16 + c0] = a1[r];
            }
        };

        LOADF(0);
        XG(0);                    // zX(0)
        LOADF(1);                 // A-frags for zX(1), consumed at t=0
        __syncthreads();

        for (int t = 0; t < T_STEPS; ++t) {
            const int p = t & 1;
            if (t + 1 < T_STEPS) XG(p ^ 1);      // zX(t+1) from prefetched afr
            if (t + 2 < T_STEPS) LOADF(t + 2);   // prefetch (hidden by next step)
            asm volatile("s_waitcnt lgkmcnt(0)\ns_barrier" ::: "memory");
            __builtin_amdgcn_sched_barrier(0);
        }
    }
}

// ---------------------------------------------------------------------------
extern "C" void kernel_launch(void* const* d_in, const int* in_sizes, int n_in,
                              void* d_out, int out_size, void* d_ws, size_t ws_size,
                              hipStream_t stream)
{
    const float* x    = (const float*)d_in[0];
    const float* ln_g = (const float*)d_in[1];
    const float* ln_b = (const float*)d_in[2];
    const float* Wf   = (const float*)d_in[3];
    const float* bf_  = (const float*)d_in[4];
    const float* Wi   = (const float*)d_in[5];
    const float* bi_  = (const float*)d_in[6];
    const float* Wg   = (const float*)d_in[7];
    const float* bg_  = (const float*)d_in[8];
    const float* Wo   = (const float*)d_in[9];
    const float* bo_  = (const float*)d_in[10];

    char* ws = (char*)d_ws;
    size_t off = 0;
    auto take = [&](size_t bytes) -> char* {
        char* p = ws + off;
        off += (bytes + 255) & ~(size_t)255;
        return p;
    };
    __hip_bfloat16* pack = (__hip_bfloat16*)take((size_t)2097152 * 2); // 4 MB
    float* S             = (float*)take(2048 * 4);
    float* C             = (float*)take(2048 * 4);
    __hip_bfloat16* xb   = (__hip_bfloat16*)take((size_t)33554432 * 2); // 64 MB
    float* sx            = (float*)take(65536 * 4);
    float* sq            = (float*)take(65536 * 4);
    char* ctrl = ws + off;
    unsigned short* hxb  = (unsigned short*)take((size_t)2 * 64 * 512 * 2); // 128 KB
    unsigned int* flags  = (unsigned int*)take(64 * 64);                    // 4 KB
    size_t ctrl_bytes = (size_t)((ws + off) - ctrl);

    hipMemsetAsync(ctrl, 0, ctrl_bytes, stream);
    pack_weights<<<dim3(128), dim3(256), 0, stream>>>(Wf, Wi, Wg, Wo, ln_g, pack);
    compute_sc<<<dim3(8), dim3(256), 0, stream>>>(Wf, Wi, Wg, Wo, bf_, bi_, bg_, bo_,
                                                  ln_g, ln_b, S, C);
    prep_x<<<dim3(16384), dim3(256), 0, stream>>>(x, xb, sx, sq);
    qlstm_main<<<dim3(NWG), dim3(512), 0, stream>>>(x, pack, S, C, xb, sx, sq,
                                                    hxb, flags, (float*)d_out);
}

// Round 8
// 10606.008 us; speedup vs baseline: 1.3289x; 1.3289x over previous
//
#include <hip/hip_runtime.h>
#include <hip/hip_bf16.h>

#define T_STEPS 1024
#define NWG     64

typedef __attribute__((ext_vector_type(8))) short          bf16x8;
typedef __attribute__((ext_vector_type(4))) float          f32x4;
typedef __attribute__((ext_vector_type(8))) unsigned short u16x8;
typedef unsigned long long ull;

static __device__ __forceinline__ unsigned short f2bf_bits(float f) {
    union { __hip_bfloat16 h; unsigned short u; } cv;
    cv.h = __float2bfloat16(f);
    return cv.u;
}

// ---------------------------------------------------------------------------
// P1: fold ln_g into weights, cast bf16, emit in MFMA B-fragment order.
// Chunk layout: [g][part][tn][kstep][lane][e]
//   k  = part*512 + kstep*32 + (lane>>4)*8 + e
//   c  = tn*16 + (lane&15);  n = (c>>3)*512 + g*8 + (c&7)
// ---------------------------------------------------------------------------
__global__ __launch_bounds__(256) void pack_weights(
    const float* __restrict__ Wf, const float* __restrict__ Wi,
    const float* __restrict__ Wg, const float* __restrict__ Wo,
    const float* __restrict__ ln_g, __hip_bfloat16* __restrict__ pack)
{
    __shared__ unsigned short tile[512 * 32];   // [k_local][c]
    const int blk = blockIdx.x;
    const int g = blk >> 1, part = blk & 1;
    const int tid = threadIdx.x;

    for (int idx = tid; idx < 512 * 32; idx += 256) {
        int kl = idx >> 5, c = idx & 31;
        int q = c >> 3, jl = c & 7;
        int k = part * 512 + kl;
        const float* W = (q == 0) ? Wf : ((q == 1) ? Wi : ((q == 2) ? Wg : Wo));
        float v = W[k * 512 + g * 8 + jl] * ln_g[k];
        tile[kl * 32 + c] = f2bf_bits(v);
    }
    __syncthreads();

    unsigned short* out = (unsigned short*)(pack + (size_t)blk * 16384);
    for (int s = tid; s < 2048; s += 256) {        // slot = tn*1024 + ks*64 + l
        int tn = s >> 10, ks = (s >> 6) & 15, l = s & 63;
        u16x8 v;
#pragma unroll
        for (int e = 0; e < 8; ++e) {
            int klocal = ks * 32 + ((l >> 4) * 8) + e;
            int c = tn * 16 + (l & 15);
            v[e] = tile[klocal * 32 + c];
        }
        *(u16x8*)(out + (size_t)s * 8) = v;
    }
}

// ---------------------------------------------------------------------------
// P2: S[n] = sum_k ln_g[k]*W[k,n],  C[n] = sum_k ln_b[k]*W[k,n] + bias[n]
// ---------------------------------------------------------------------------
__global__ __launch_bounds__(256) void compute_sc(
    const float* __restrict__ Wf, const float* __restrict__ Wi,
    const float* __restrict__ Wg, const float* __restrict__ Wo,
    const float* __restrict__ bf_, const float* __restrict__ bi_,
    const float* __restrict__ bg_, const float* __restrict__ bo_,
    const float* __restrict__ ln_g, const float* __restrict__ ln_b,
    float* __restrict__ S, float* __restrict__ C)
{
    int n = blockIdx.x * 256 + threadIdx.x;        // 0..2047
    int q = n >> 9, j = n & 511;
    const float* W = (q == 0) ? Wf : ((q == 1) ? Wi : ((q == 2) ? Wg : Wo));
    const float* bb = (q == 0) ? bf_ : ((q == 1) ? bi_ : ((q == 2) ? bg_ : bo_));
    float accS = 0.f, accC = 0.f;
    for (int k = 0; k < 1024; ++k) {
        float w = W[k * 512 + j];
        accS += ln_g[k] * w;
        accC += ln_b[k] * w;
    }
    S[n] = accS;
    C[n] = accC + bb[j];
}

// ---------------------------------------------------------------------------
// P3: x -> bf16 copy + per-row sum / sumsq (fp32). One wave per (t,b) row.
// ---------------------------------------------------------------------------
__global__ __launch_bounds__(256) void prep_x(
    const float* __restrict__ x, __hip_bfloat16* __restrict__ xb,
    float* __restrict__ sx, float* __restrict__ sq)
{
    const int wave = threadIdx.x >> 6, lane = threadIdx.x & 63;
    const long row = (long)blockIdx.x * 4 + wave;  // 0..65535
    const float* src = x + row * 512 + lane * 8;
    float4 a = *(const float4*)src;
    float4 b = *(const float4*)(src + 4);
    float vals[8] = {a.x, a.y, a.z, a.w, b.x, b.y, b.z, b.w};
    u16x8 o;
    float s = 0.f, qq = 0.f;
#pragma unroll
    for (int e = 0; e < 8; ++e) {
        s += vals[e];
        qq += vals[e] * vals[e];
        o[e] = f2bf_bits(vals[e]);
    }
    *(u16x8*)((unsigned short*)xb + row * 512 + lane * 8) = o;
#pragma unroll
    for (int d = 1; d < 64; d <<= 1) {
        s  += __shfl_xor(s, d);
        qq += __shfl_xor(qq, d);
    }
    if (lane == 0) { sx[row] = s; sq[row] = qq; }
}

// ---------------------------------------------------------------------------
// Main persistent kernel: 64 WGs x 512 threads (R7 structure, write fixed).
// Waves 0-3 = h-waves (m = wave): FULL-K h-GEMM for rows [16m,16m+16),
//   local LN stats, gates, publish, per-(WG,m) flag — no __syncthreads on
//   the critical path. Consumer wave m waits only on producer waves m.
// Waves 4-7 = x-waves: zX(t+1) in shadow with prefetched A-frags.
// stacked[t-1] written by consumers from loaded h words, PARTITIONED:
//   WG g owns cols [g*8,g*8+8) = (acol=(g&3)*8, ks=g>>2) -> 2 KB/WG/step.
// ---------------------------------------------------------------------------
__global__ __launch_bounds__(512, 2) void qlstm_main(
    const float* __restrict__ x,
    const __hip_bfloat16* __restrict__ pack,
    const float* __restrict__ Sarr, const float* __restrict__ Carr,
    const __hip_bfloat16* __restrict__ xb,
    const float* __restrict__ sx, const float* __restrict__ sq,
    unsigned short* __restrict__ hxb,   // [2][64][512] bf16 (zeroed)
    unsigned int* __restrict__ flags,   // [64 WG][16 u32] (zeroed)
    float* __restrict__ out)            // stacked | hx | cx (fp32)
{
    const int g = blockIdx.x;
    const int tid = threadIdx.x;
    const int wave = tid >> 6, lane = tid & 63;
    const bool isH = wave < 4;
    const int m = isH ? wave : (wave - 4);

    __shared__ float zXs[2][64][33];    // [parity][row][col32]
    __shared__ float zHs[64][33];
    __shared__ float rsS[64], rsQ[64];
    __shared__ float Scol[32], Ccol[32];

    const int arow = m * 16 + (lane & 15);
    const int acol = (lane >> 4) * 8;
    const int r0l = (lane >> 4) * 4, c0 = lane & 15;
    const int grow = m * 16 + (lane >> 2);   // gate row
    const int gcp  = (lane & 3) * 2;         // gate col pair (WG-local)

    if (isH) {
        if (wave == 0 && lane < 32) {
            int n = (lane >> 3) * 512 + g * 8 + (lane & 7);
            Scol[lane] = Sarr[n];
            Ccol[lane] = Carr[n];
        }
        // Full-K h B-fragments: 2 ntiles x 16 ksteps x 4 VGPR = 128 VGPR.
        bf16x8 Bh0[16], Bh1[16];
        {
            const bf16x8* ph = (const bf16x8*)(pack + (size_t)(g * 2 + 1) * 16384);
#pragma unroll
            for (int ks = 0; ks < 16; ++ks) {
                Bh0[ks] = ph[ks * 64 + lane];
                Bh1[ks] = ph[1024 + ks * 64 + lane];
            }
        }
        float cxA = 0.f, cxB = 0.f;
        __syncthreads();

        for (int t = 0; t < T_STEPS; ++t) {
            const int p = t & 1;

            // recurrence-independent loads (nt), issued before the spin
            const float* xp = x + (size_t)t * 32768 + grow * 512 + g * 8 + gcp;
            float xr0 = __builtin_nontemporal_load(xp);
            float xr1 = __builtin_nontemporal_load(xp + 1);
            float sxv = __builtin_nontemporal_load(sx + t * 64 + grow);
            float sqv = __builtin_nontemporal_load(sq + t * 64 + grow);

            // ---- spin: lane l polls flags[l][m] only ----
            if (t) {
                const unsigned int* fp_ = flags + lane * 16 + m;
                int slp = 0;
                for (;;) {
                    unsigned f = __hip_atomic_load(fp_, __ATOMIC_RELAXED,
                                                   __HIP_MEMORY_SCOPE_AGENT);
                    if (__all((int)f >= t)) break;
                    if      (slp == 0) __builtin_amdgcn_s_sleep(1);
                    else if (slp == 1) __builtin_amdgcn_s_sleep(2);
                    else if (slp == 2) __builtin_amdgcn_s_sleep(4);
                    else               __builtin_amdgcn_s_sleep(8);
                    if (slp < 3) ++slp;
                }
                asm volatile("" ::: "memory");
            }

            // ---- coherent h loads: full row slice, 32 x 8B per lane ----
            ull hw[32];
            {
                const ull* hp = (const ull*)hxb + (size_t)p * 8192;
                const int eb = (arow * 512 + acol) >> 2;
#pragma unroll
                for (int ks = 0; ks < 16; ++ks) {
                    hw[2 * ks]     = __hip_atomic_load(hp + eb + ks * 8,
                                        __ATOMIC_RELAXED, __HIP_MEMORY_SCOPE_AGENT);
                    hw[2 * ks + 1] = __hip_atomic_load(hp + eb + ks * 8 + 1,
                                        __ATOMIC_RELAXED, __HIP_MEMORY_SCOPE_AGENT);
                }
            }

            // ---- h-GEMM (full K, 32 MFMA) ----
            f32x4 h0 = {0.f, 0.f, 0.f, 0.f}, h1 = {0.f, 0.f, 0.f, 0.f};
#pragma unroll
            for (int ks = 0; ks < 16; ++ks) {
                union { ull u[2]; bf16x8 v; } cv;
                cv.u[0] = hw[2 * ks]; cv.u[1] = hw[2 * ks + 1];
                h0 = __builtin_amdgcn_mfma_f32_16x16x32_bf16(cv.v, Bh0[ks], h0, 0, 0, 0);
                h1 = __builtin_amdgcn_mfma_f32_16x16x32_bf16(cv.v, Bh1[ks], h1, 0, 0, 0);
            }

            // ---- local LN stats (full row within 4 lanes) ----
            {
                float s = 0.f, q = 0.f;
#pragma unroll
                for (int i = 0; i < 32; ++i) {
                    unsigned lo = (unsigned)hw[i], hi = (unsigned)(hw[i] >> 32);
                    float f0 = __uint_as_float(lo << 16);
                    float f1 = __uint_as_float(lo & 0xffff0000u);
                    float f2 = __uint_as_float(hi << 16);
                    float f3 = __uint_as_float(hi & 0xffff0000u);
                    s += (f0 + f1) + (f2 + f3);
                    q = fmaf(f0, f0, fmaf(f1, f1, fmaf(f2, f2, fmaf(f3, f3, q))));
                }
                s += __shfl_xor(s, 16); q += __shfl_xor(q, 16);
                s += __shfl_xor(s, 32); q += __shfl_xor(q, 32);
                if (lane < 16) { rsS[m * 16 + lane] = s; rsQ[m * 16 + lane] = q; }
            }

            // ---- zH dump (same-wave rows only; no barrier needed) ----
#pragma unroll
            for (int r = 0; r < 4; ++r) {
                zHs[m * 16 + r0l + r][c0]      = h0[r];
                zHs[m * 16 + r0l + r][16 + c0] = h1[r];
            }

            // ---- gates for (grow, cols g*8+gcp, +1) ----
            float hv0, hv1;
            {
                float hs = rsS[grow], hq = rsQ[grow];
                float mu = (sxv + hs) * (1.f / 1024.f);
                float var = (sqv + hq) * (1.f / 1024.f) - mu * mu;
                float rs = rsqrtf(var + 1e-5f);
#pragma unroll
                for (int d = 0; d < 2; ++d) {
                    int cl = gcp + d;
                    float z0 = zXs[p][grow][cl]      + zHs[grow][cl];
                    float z1 = zXs[p][grow][8 + cl]  + zHs[grow][8 + cl];
                    float z2 = zXs[p][grow][16 + cl] + zHs[grow][16 + cl];
                    float z3 = zXs[p][grow][24 + cl] + zHs[grow][24 + cl];
                    float zf = rs * (z0 - mu * Scol[cl])      + Ccol[cl];
                    float zi = rs * (z1 - mu * Scol[8 + cl])  + Ccol[8 + cl];
                    float zg = rs * (z2 - mu * Scol[16 + cl]) + Ccol[16 + cl];
                    float zo = rs * (z3 - mu * Scol[24 + cl]) + Ccol[24 + cl];
                    float f  = 1.f / (1.f + __expf(-zf));
                    float i_ = 1.f / (1.f + __expf(-zi));
                    float gg = 2.f / (1.f + __expf(-2.f * zg)) - 1.f;
                    float o_ = 1.f / (1.f + __expf(-zo));
                    float cxv = (d == 0) ? cxA : cxB;
                    cxv = f * cxv + i_ * gg;
                    float th = 2.f / (1.f + __expf(-2.f * cxv)) - 1.f;
                    float hvv = o_ * th + ((d == 0) ? xr0 : xr1);
                    if (d == 0) { cxA = cxv; hv0 = hvv; }
                    else        { cxB = cxv; hv1 = hvv; }
                }
            }

            // ---- publish (sc1) + drain + per-wave flag ----
            if (t + 1 < T_STEPS) {
                unsigned vv = (unsigned)f2bf_bits(hv0) |
                              ((unsigned)f2bf_bits(hv1) << 16);
                ull v01 = (ull)vv |
                    ((ull)(unsigned)__shfl_xor((int)vv, 1) << 32);
                if ((lane & 1) == 0) {
                    ull* hd = (ull*)hxb +
                        (((size_t)(p ^ 1) * 32768 + grow * 512 + g * 8 + gcp) >> 2);
                    __hip_atomic_store(hd, v01, __ATOMIC_RELAXED,
                                       __HIP_MEMORY_SCOPE_AGENT);
                }
                asm volatile("s_waitcnt vmcnt(0)" ::: "memory");
                if (lane == 0) {
                    __hip_atomic_store(flags + g * 16 + m, (unsigned)(t + 1),
                                       __ATOMIC_RELAXED, __HIP_MEMORY_SCOPE_AGENT);
                }
            }

            // ---- shadow: stacked[t-1], PARTITIONED (WG g owns its 8 cols) ----
            if (t && (lane >> 4) == (g & 3)) {
                const int ksg = g >> 2;
                ull w0 = hw[2 * ksg], w1 = hw[2 * ksg + 1];
                f32x4 o0, o1;
                unsigned lo = (unsigned)w0, hi = (unsigned)(w0 >> 32);
                o0[0] = __uint_as_float(lo << 16);
                o0[1] = __uint_as_float(lo & 0xffff0000u);
                o0[2] = __uint_as_float(hi << 16);
                o0[3] = __uint_as_float(hi & 0xffff0000u);
                lo = (unsigned)w1; hi = (unsigned)(w1 >> 32);
                o1[0] = __uint_as_float(lo << 16);
                o1[1] = __uint_as_float(lo & 0xffff0000u);
                o1[2] = __uint_as_float(hi << 16);
                o1[3] = __uint_as_float(hi & 0xffff0000u);
                float* ob = out + (size_t)(t - 1) * 32768 + arow * 512
                          + acol + ksg * 32;
                __builtin_nontemporal_store(o0, (f32x4*)ob);
                __builtin_nontemporal_store(o1, (f32x4*)(ob + 4));
            }
            if (t == T_STEPS - 1) {
                size_t b0 = (size_t)(T_STEPS - 1) * 32768 + grow * 512 + g * 8 + gcp;
                out[b0] = hv0; out[b0 + 1] = hv1;
                size_t b1 = (size_t)T_STEPS * 32768 + grow * 512 + g * 8 + gcp;
                out[b1] = hv0; out[b1 + 1] = hv1;
                out[b1 + 32768] = cxA; out[b1 + 32769] = cxB;
            }

            asm volatile("s_waitcnt lgkmcnt(0)\ns_barrier" ::: "memory");
            __builtin_amdgcn_sched_barrier(0);
        }
    } else {
        // ---------------- x-waves ----------------
        bf16x8 Bx0[16], Bx1[16];
        {
            const bf16x8* px = (const bf16x8*)(pack + (size_t)(g * 2 + 0) * 16384);
#pragma unroll
            for (int ks = 0; ks < 16; ++ks) {
                Bx0[ks] = px[ks * 64 + lane];
                Bx1[ks] = px[1024 + ks * 64 + lane];
            }
        }
        bf16x8 afr[16];
        auto LOADF = [&](int tt) {
            const bf16x8* Ap = (const bf16x8*)(xb + (size_t)tt * 32768
                                               + arow * 512 + acol);
#pragma unroll
            for (int ks = 0; ks < 16; ++ks)
                afr[ks] = __builtin_nontemporal_load(Ap + ks * 4);
        };
        auto XG = [&](int par) {
            f32x4 a0 = {0.f, 0.f, 0.f, 0.f}, a1 = {0.f, 0.f, 0.f, 0.f};
#pragma unroll
            for (int ks = 0; ks < 16; ++ks) {
                a0 = __builtin_amdgcn_mfma_f32_16x16x32_bf16(afr[ks], Bx0[ks], a0, 0, 0, 0);
                a1 = __builtin_amdgcn_mfma_f32_16x16x32_bf16(afr[ks], Bx1[ks], a1, 0, 0, 0);
            }
#pragma unroll
            for (int r = 0; r < 4; ++r) {
                zXs[par][m * 16 + r0l + r][c0]      = a0[r];
                zXs[par][m * 16 + r0l + r][16 + c0] = a1[r];
            }
        };

        LOADF(0);
        XG(0);                    // zX(0)
        LOADF(1);                 // A-frags for zX(1), consumed at t=0
        __syncthreads();

        for (int t = 0; t < T_STEPS; ++t) {
            const int p = t & 1;
            if (t + 1 < T_STEPS) XG(p ^ 1);      // zX(t+1) from prefetched afr
            if (t + 2 < T_STEPS) LOADF(t + 2);   // prefetch (hidden by next step)
            asm volatile("s_waitcnt lgkmcnt(0)\ns_barrier" ::: "memory");
            __builtin_amdgcn_sched_barrier(0);
        }
    }
}

// ---------------------------------------------------------------------------
extern "C" void kernel_launch(void* const* d_in, const int* in_sizes, int n_in,
                              void* d_out, int out_size, void* d_ws, size_t ws_size,
                              hipStream_t stream)
{
    const float* x    = (const float*)d_in[0];
    const float* ln_g = (const float*)d_in[1];
    const float* ln_b = (const float*)d_in[2];
    const float* Wf   = (const float*)d_in[3];
    const float* bf_  = (const float*)d_in[4];
    const float* Wi   = (const float*)d_in[5];
    const float* bi_  = (const float*)d_in[6];
    const float* Wg   = (const float*)d_in[7];
    const float* bg_  = (const float*)d_in[8];
    const float* Wo   = (const float*)d_in[9];
    const float* bo_  = (const float*)d_in[10];

    char* ws = (char*)d_ws;
    size_t off = 0;
    auto take = [&](size_t bytes) -> char* {
        char* p = ws + off;
        off += (bytes + 255) & ~(size_t)255;
        return p;
    };
    __hip_bfloat16* pack = (__hip_bfloat16*)take((size_t)2097152 * 2); // 4 MB
    float* S             = (float*)take(2048 * 4);
    float* C             = (float*)take(2048 * 4);
    __hip_bfloat16* xb   = (__hip_bfloat16*)take((size_t)33554432 * 2); // 64 MB
    float* sx            = (float*)take(65536 * 4);
    float* sq            = (float*)take(65536 * 4);
    char* ctrl = ws + off;
    unsigned short* hxb  = (unsigned short*)take((size_t)2 * 64 * 512 * 2); // 128 KB
    unsigned int* flags  = (unsigned int*)take(64 * 64);                    // 4 KB
    size_t ctrl_bytes = (size_t)((ws + off) - ctrl);

    hipMemsetAsync(ctrl, 0, ctrl_bytes, stream);
    pack_weights<<<dim3(128), dim3(256), 0, stream>>>(Wf, Wi, Wg, Wo, ln_g, pack);
    compute_sc<<<dim3(8), dim3(256), 0, stream>>>(Wf, Wi, Wg, Wo, bf_, bi_, bg_, bo_,
                                                  ln_g, ln_b, S, C);
    prep_x<<<dim3(16384), dim3(256), 0, stream>>>(x, xb, sx, sq);
    qlstm_main<<<dim3(NWG), dim3(512), 0, stream>>>(x, pack, S, C, xb, sx, sq,
                                                    hxb, flags, (float*)d_out);
}

// Round 12
// 10265.791 us; speedup vs baseline: 1.3729x; 1.0331x over previous
//
#include <hip/hip_runtime.h>
#include <hip/hip_bf16.h>

#define T_STEPS 1024

typedef __attribute__((ext_vector_type(8))) short          bf16x8;
typedef __attribute__((ext_vector_type(4))) float          f32x4;
typedef __attribute__((ext_vector_type(8))) unsigned short u16x8;
typedef unsigned long long ull;

static __device__ __forceinline__ unsigned short f2bf_bits(float f) {
    union { __hip_bfloat16 h; unsigned short u; } cv;
    cv.h = __float2bfloat16(f);
    return cv.u;
}

// ---------------------------------------------------------------------------
// P1: fold ln_g into weights, cast bf16, emit in MFMA B-fragment order.
// Chunk layout: [g][part][tn][kstep][lane][e]
//   k  = part*512 + kstep*32 + (lane>>4)*8 + e
//   c  = tn*16 + (lane&15);  n = (c>>3)*512 + g*8 + (c&7)
// ---------------------------------------------------------------------------
__global__ __launch_bounds__(256) void pack_weights(
    const float* __restrict__ Wf, const float* __restrict__ Wi,
    const float* __restrict__ Wg, const float* __restrict__ Wo,
    const float* __restrict__ ln_g, __hip_bfloat16* __restrict__ pack)
{
    __shared__ unsigned short tile[512 * 32];   // [k_local][c]
    const int blk = blockIdx.x;
    const int g = blk >> 1, part = blk & 1;
    const int tid = threadIdx.x;

    for (int idx = tid; idx < 512 * 32; idx += 256) {
        int kl = idx >> 5, c = idx & 31;
        int q = c >> 3, jl = c & 7;
        int k = part * 512 + kl;
        const float* W = (q == 0) ? Wf : ((q == 1) ? Wi : ((q == 2) ? Wg : Wo));
        float v = W[k * 512 + g * 8 + jl] * ln_g[k];
        tile[kl * 32 + c] = f2bf_bits(v);
    }
    __syncthreads();

    unsigned short* out = (unsigned short*)(pack + (size_t)blk * 16384);
    for (int s = tid; s < 2048; s += 256) {        // slot = tn*1024 + ks*64 + l
        int tn = s >> 10, ks = (s >> 6) & 15, l = s & 63;
        u16x8 v;
#pragma unroll
        for (int e = 0; e < 8; ++e) {
            int klocal = ks * 32 + ((l >> 4) * 8) + e;
            int c = tn * 16 + (l & 15);
            v[e] = tile[klocal * 32 + c];
        }
        *(u16x8*)(out + (size_t)s * 8) = v;
    }
}

// ---------------------------------------------------------------------------
// P2: S[n] = sum_k ln_g[k]*W[k,n],  C[n] = sum_k ln_b[k]*W[k,n] + bias[n]
// ---------------------------------------------------------------------------
__global__ __launch_bounds__(256) void compute_sc(
    const float* __restrict__ Wf, const float* __restrict__ Wi,
    const float* __restrict__ Wg, const float* __restrict__ Wo,
    const float* __restrict__ bf_, const float* __restrict__ bi_,
    const float* __restrict__ bg_, const float* __restrict__ bo_,
    const float* __restrict__ ln_g, const float* __restrict__ ln_b,
    float* __restrict__ S, float* __restrict__ C)
{
    int n = blockIdx.x * 256 + threadIdx.x;        // 0..2047
    int q = n >> 9, j = n & 511;
    const float* W = (q == 0) ? Wf : ((q == 1) ? Wi : ((q == 2) ? Wg : Wo));
    const float* bb = (q == 0) ? bf_ : ((q == 1) ? bi_ : ((q == 2) ? bg_ : bo_));
    float accS = 0.f, accC = 0.f;
    for (int k = 0; k < 1024; ++k) {
        float w = W[k * 512 + j];
        accS += ln_g[k] * w;
        accC += ln_b[k] * w;
    }
    S[n] = accS;
    C[n] = accC + bb[j];
}

// ---------------------------------------------------------------------------
// P3: x -> bf16 copy + per-row sum / sumsq (fp32). One wave per (t,b) row.
// ---------------------------------------------------------------------------
__global__ __launch_bounds__(256) void prep_x(
    const float* __restrict__ x, __hip_bfloat16* __restrict__ xb,
    float* __restrict__ sx, float* __restrict__ sq)
{
    const int wave = threadIdx.x >> 6, lane = threadIdx.x & 63;
    const long row = (long)blockIdx.x * 4 + wave;  // 0..65535
    const float* src = x + row * 512 + lane * 8;
    float4 a = *(const float4*)src;
    float4 b = *(const float4*)(src + 4);
    float vals[8] = {a.x, a.y, a.z, a.w, b.x, b.y, b.z, b.w};
    u16x8 o;
    float s = 0.f, qq = 0.f;
#pragma unroll
    for (int e = 0; e < 8; ++e) {
        s += vals[e];
        qq += vals[e] * vals[e];
        o[e] = f2bf_bits(vals[e]);
    }
    *(u16x8*)((unsigned short*)xb + row * 512 + lane * 8) = o;
#pragma unroll
    for (int d = 1; d < 64; d <<= 1) {
        s  += __shfl_xor(s, d);
        qq += __shfl_xor(qq, d);
    }
    if (lane == 0) { sx[row] = s; sq[row] = qq; }
}

// ---------------------------------------------------------------------------
// Per-timestep kernel: 64 WGs x 512 thr. Kernel boundary IS the global sync
// (device-wide release/acquire at dispatch edges — no atomics, no spinning).
// Wave w: m = w>>1 (16-row M tile), part = w&1 (0: x·Wx from xb[t],
// 1: h·Wh from hxb[p]). Part-1 waves also compute LN row stats locally from
// the h words they load anyway. One __syncthreads, then gates per thread
// (b = tid>>3, jl = tid&7), cx carried in global f32, h published as bf16.
// ---------------------------------------------------------------------------
__global__ __launch_bounds__(512) void qlstm_step(
    int t,
    const float* __restrict__ x,
    const __hip_bfloat16* __restrict__ pack,
    const float* __restrict__ Sarr, const float* __restrict__ Carr,
    const __hip_bfloat16* __restrict__ xb,
    const float* __restrict__ sx, const float* __restrict__ sq,
    __hip_bfloat16* __restrict__ hxb,   // [2][64][512] bf16 (zeroed once)
    float* __restrict__ cxg,            // [64][512] f32 (zeroed once)
    float* __restrict__ out)            // stacked | hx | cx (fp32)
{
    const int g = blockIdx.x;
    const int tid = threadIdx.x;
    const int wave = tid >> 6, lane = tid & 63;
    const int m = wave >> 1, part = wave & 1;
    const int b = tid >> 3, jl = tid & 7, jg = g * 8 + jl;
    const int p = t & 1;

    __shared__ float zc[2][64 * 33];    // [part][row*33+col32]
    __shared__ float rsS[64], rsQ[64];
    __shared__ float Scol[32], Ccol[32];

    if (tid < 32) {
        int n = (tid >> 3) * 512 + g * 8 + (tid & 7);
        Scol[tid] = Sarr[n];
        Ccol[tid] = Carr[n];
    }

    const int arow = m * 16 + (lane & 15);
    const int acol = (lane >> 4) * 8;
    const int r0 = m * 16 + (lane >> 4) * 4, c0 = lane & 15;

    // ---- per-thread gate-side loads (issue early) ----
    float sxv = sx[t * 64 + b];
    float sqv = sq[t * 64 + b];
    float xres = x[(size_t)t * 32768 + b * 512 + jg];
    float cx = cxg[b * 512 + jg];

    // ---- A-frag loads (16 ksteps x 16B per lane) ----
    ull w0[16], w1[16];
    {
        const __hip_bfloat16* Ab =
            part ? (hxb + (size_t)p * 32768) : (xb + (size_t)t * 32768);
        const ull* Ap = (const ull*)Ab;
        const int eb = (arow * 512 + acol) >> 2;
#pragma unroll
        for (int ks = 0; ks < 16; ++ks) {
            w0[ks] = Ap[eb + ks * 8];
            w1[ks] = Ap[eb + ks * 8 + 1];
        }
    }

    // ---- GEMM: 32 MFMA per wave over K=512 of this part ----
    {
        const bf16x8* Pb = (const bf16x8*)(pack + (size_t)(g * 2 + part) * 16384);
        f32x4 a0 = {0.f, 0.f, 0.f, 0.f}, a1 = {0.f, 0.f, 0.f, 0.f};
#pragma unroll
        for (int ks = 0; ks < 16; ++ks) {
            union { ull u[2]; bf16x8 v; } cv;
            cv.u[0] = w0[ks]; cv.u[1] = w1[ks];
            a0 = __builtin_amdgcn_mfma_f32_16x16x32_bf16(cv.v, Pb[ks * 64 + lane], a0, 0, 0, 0);
            a1 = __builtin_amdgcn_mfma_f32_16x16x32_bf16(cv.v, Pb[1024 + ks * 64 + lane], a1, 0, 0, 0);
        }
        float* zb = &zc[part][0];
#pragma unroll
        for (int r = 0; r < 4; ++r) {
            zb[(r0 + r) * 33 + c0]      = a0[r];
            zb[(r0 + r) * 33 + 16 + c0] = a1[r];
        }
    }

    // ---- LN stats (part-1 waves, from loaded h words; 4 lanes share a row) ----
    if (part) {
        float s = 0.f, q = 0.f;
#pragma unroll
        for (int ks = 0; ks < 16; ++ks) {
            unsigned uu[4] = { (unsigned)w0[ks], (unsigned)(w0[ks] >> 32),
                               (unsigned)w1[ks], (unsigned)(w1[ks] >> 32) };
#pragma unroll
            for (int j = 0; j < 4; ++j) {
                float f0 = __uint_as_float(uu[j] << 16);
                float f1 = __uint_as_float(uu[j] & 0xffff0000u);
                s += f0 + f1;
                q = fmaf(f0, f0, fmaf(f1, f1, q));
            }
        }
        s += __shfl_xor(s, 16); q += __shfl_xor(q, 16);
        s += __shfl_xor(s, 32); q += __shfl_xor(q, 32);
        if (lane < 16) { rsS[m * 16 + lane] = s; rsQ[m * 16 + lane] = q; }
    }
    __syncthreads();

    // ---- gates / state update (thread owns (b, jg)) ----
    {
        float hs = rsS[b], hq = rsQ[b];
        float mu = (sxv + hs) * (1.f / 1024.f);
        float var = (sqv + hq) * (1.f / 1024.f) - mu * mu;
        float rs = rsqrtf(var + 1e-5f);

        const float* z0 = &zc[0][0];
        const float* z1 = &zc[1][0];
        const int i0 = b * 33;
        float zf = z0[i0 + jl]      + z1[i0 + jl];
        float zi = z0[i0 + 8 + jl]  + z1[i0 + 8 + jl];
        float zg = z0[i0 + 16 + jl] + z1[i0 + 16 + jl];
        float zo = z0[i0 + 24 + jl] + z1[i0 + 24 + jl];
        zf = rs * (zf - mu * Scol[jl])      + Ccol[jl];
        zi = rs * (zi - mu * Scol[8 + jl])  + Ccol[8 + jl];
        zg = rs * (zg - mu * Scol[16 + jl]) + Ccol[16 + jl];
        zo = rs * (zo - mu * Scol[24 + jl]) + Ccol[24 + jl];

        float f  = 1.f / (1.f + __expf(-zf));
        float i_ = 1.f / (1.f + __expf(-zi));
        float gg = 2.f / (1.f + __expf(-2.f * zg)) - 1.f;
        float o_ = 1.f / (1.f + __expf(-zo));
        cx = f * cx + i_ * gg;
        float th = 2.f / (1.f + __expf(-2.f * cx)) - 1.f;
        float hval = o_ * th + xres;

        cxg[b * 512 + jg] = cx;
        hxb[(size_t)(p ^ 1) * 32768 + b * 512 + jg] = __float2bfloat16(hval);
        out[(size_t)t * 32768 + b * 512 + jg] = hval;
        if (t == T_STEPS - 1) {
            out[(size_t)T_STEPS * 32768 + b * 512 + jg] = hval;
            out[(size_t)T_STEPS * 32768 + 32768 + b * 512 + jg] = cx;
        }
    }
}

// ---------------------------------------------------------------------------
extern "C" void kernel_launch(void* const* d_in, const int* in_sizes, int n_in,
                              void* d_out, int out_size, void* d_ws, size_t ws_size,
                              hipStream_t stream)
{
    const float* x    = (const float*)d_in[0];
    const float* ln_g = (const float*)d_in[1];
    const float* ln_b = (const float*)d_in[2];
    const float* Wf   = (const float*)d_in[3];
    const float* bf_  = (const float*)d_in[4];
    const float* Wi   = (const float*)d_in[5];
    const float* bi_  = (const float*)d_in[6];
    const float* Wg   = (const float*)d_in[7];
    const float* bg_  = (const float*)d_in[8];
    const float* Wo   = (const float*)d_in[9];
    const float* bo_  = (const float*)d_in[10];

    char* ws = (char*)d_ws;
    size_t off = 0;
    auto take = [&](size_t bytes) -> char* {
        char* p = ws + off;
        off += (bytes + 255) & ~(size_t)255;
        return p;
    };
    __hip_bfloat16* pack = (__hip_bfloat16*)take((size_t)2097152 * 2); // 4 MB
    float* S             = (float*)take(2048 * 4);
    float* C             = (float*)take(2048 * 4);
    __hip_bfloat16* xb   = (__hip_bfloat16*)take((size_t)33554432 * 2); // 64 MB
    float* sx            = (float*)take(65536 * 4);
    float* sq            = (float*)take(65536 * 4);
    char* ctrl = ws + off;
    __hip_bfloat16* hxb  = (__hip_bfloat16*)take((size_t)2 * 64 * 512 * 2); // 128 KB
    float* cxg           = (float*)take((size_t)64 * 512 * 4);              // 128 KB
    size_t ctrl_bytes = (size_t)((ws + off) - ctrl);

    hipMemsetAsync(ctrl, 0, ctrl_bytes, stream);
    pack_weights<<<dim3(128), dim3(256), 0, stream>>>(Wf, Wi, Wg, Wo, ln_g, pack);
    compute_sc<<<dim3(8), dim3(256), 0, stream>>>(Wf, Wi, Wg, Wo, bf_, bi_, bg_, bo_,
                                                  ln_g, ln_b, S, C);
    prep_x<<<dim3(16384), dim3(256), 0, stream>>>(x, xb, sx, sq);
    for (int t = 0; t < T_STEPS; ++t) {
        qlstm_step<<<dim3(64), dim3(512), 0, stream>>>(
            t, x, pack, S, C, xb, sx, sq, hxb, cxg, (float*)d_out);
    }
}